// Round 11
// baseline (195.754 us; speedup 1.0000x reference)
//
#include <hip/hip_runtime.h>
#include <hip/hip_bf16.h>
#include <math.h>

typedef __attribute__((ext_vector_type(8))) __bf16 bf16x8;
typedef __attribute__((ext_vector_type(4))) __bf16 bf16x4;
typedef __attribute__((ext_vector_type(2))) __bf16 bf16x2;
typedef __attribute__((ext_vector_type(4))) float f32x4;

#define NPTS 1024
#define CIN 512
#define NSAMP 64
#define LDFT 520
#define LDFO 136

__device__ __forceinline__ void local_coords(const float* q, float cx, float cy, float cz,
                                             const float R[9], float& l0, float& l1, float& l2) {
    float d0 = __fsub_rn(q[0], cx);
    float d1 = __fsub_rn(q[1], cy);
    float d2 = __fsub_rn(q[2], cz);
    l0 = __fadd_rn(__fadd_rn(__fmul_rn(d0, R[0]), __fmul_rn(d1, R[3])), __fmul_rn(d2, R[6]));
    l1 = __fadd_rn(__fadd_rn(__fmul_rn(d0, R[1]), __fmul_rn(d1, R[4])), __fmul_rn(d2, R[7]));
    l2 = __fadd_rn(__fadd_rn(__fmul_rn(d0, R[2]), __fmul_rn(d1, R[5])), __fmul_rn(d2, R[8]));
}

// -------- setup: blocks [0,256) = prep; blocks [256,2304) = select --------
__global__ __launch_bounds__(256) void setup_kernel(
    const float* __restrict__ xyz, const float* __restrict__ rot,
    const float* __restrict__ crop,
    const float* __restrict__ W1, const float* __restrict__ W2,
    const float* __restrict__ g1, const float* __restrict__ be1,
    const float* __restrict__ m1, const float* __restrict__ v1,
    const float* __restrict__ g2, const float* __restrict__ be2,
    const float* __restrict__ m2, const float* __restrict__ v2,
    __bf16* __restrict__ W1f, __bf16* __restrict__ W2s,
    float* __restrict__ wxs,
    float* __restrict__ s1, float* __restrict__ b1,
    float* __restrict__ s2, float* __restrict__ b2,
    unsigned short* __restrict__ seln_g, int* __restrict__ cnt_g,
    f32x4* __restrict__ lcsel_g) {
    __shared__ __align__(16) f32x4 lcall[NPTS];
    __shared__ unsigned long long msk[16];
    __shared__ int wpre[17];
    __shared__ int selr[NSAMP];

    const int t = threadIdx.x;
    if (blockIdx.x < 256) {
        const int o = blockIdx.x;
        if (t == 0) {
            float sc1 = g1[o] / sqrtf(v1[o] + 1e-5f);
            s1[o] = sc1;
            b1[o] = be1[o] - m1[o] * sc1;
            float sc2 = g2[o] / sqrtf(v2[o] + 1e-5f);
            s2[o] = sc2;
            b2[o] = be2[o] - m2[o] * sc2;
            wxs[o * 4 + 0] = sc1 * W1[o * 515 + 0];
            wxs[o * 4 + 1] = sc1 * W1[o * 515 + 1];
            wxs[o * 4 + 2] = sc1 * W1[o * 515 + 2];
            wxs[o * 4 + 3] = 0.f;
        }
        for (int k = t; k < CIN; k += blockDim.x)
            W1f[o * CIN + k] = (__bf16)W1[o * 515 + 3 + k];
        // W2s[f]: f = ((((w*8+ks)*2+nt)*64)+l)*8 + j ; o2=w*32+nt*16+(l&15), k=ks*32+(l>>4)*8+j
        {
            const int f = o * 256 + t;
            const int j = f & 7;
            const int l = (f >> 3) & 63;
            const int nt = (f >> 9) & 1;
            const int ks = (f >> 10) & 7;
            const int w = (f >> 13) & 7;
            const int o2 = w * 32 + nt * 16 + (l & 15);
            const int k = ks * 32 + ((l >> 4) << 3) + j;
            W2s[f] = (__bf16)W2[o2 * 256 + k];
        }
        return;
    }
    const int bid = blockIdx.x - 256;
    const int b = bid >> 10;
    const int l = t & 63, w = t >> 6;

    const float cx = xyz[bid * 3 + 0], cy = xyz[bid * 3 + 1], cz = xyz[bid * 3 + 2];
    float R[9];
#pragma unroll
    for (int j = 0; j < 9; ++j) R[j] = rot[bid * 9 + j];
    const float h0 = 0.5f * crop[bid * 3 + 0];
    const float h1 = 0.5f * crop[bid * 3 + 1];
    const float h2 = 0.5f * crop[bid * 3 + 2];

#pragma unroll
    for (int i = 0; i < 4; ++i) {
        const int n = i * 256 + t;
        float l0, l1, l2;
        local_coords(xyz + (size_t)(b * NPTS + n) * 3, cx, cy, cz, R, l0, l1, l2);
        lcall[n] = f32x4{l0, l1, l2, 0.f};
        bool ins = (__builtin_fabsf(l0) <= h0) && (__builtin_fabsf(l1) <= h1) &&
                   (__builtin_fabsf(l2) <= h2);
        unsigned long long bal = __ballot(ins);
        if (l == 0) msk[i * 4 + w] = bal;
    }
    __syncthreads();
    if (t < 64) {
        const int c = (t < 16) ? __popcll(msk[t]) : 0;
        int sum = c;
#pragma unroll
        for (int d = 1; d < 16; d <<= 1) {
            int v = __shfl_up(sum, d);
            if (t >= d) sum += v;
        }
        if (t < 16) wpre[t] = sum - c;
        if (t == 15) wpre[16] = sum;
    }
    __syncthreads();
    const int cnt = wpre[16];
#pragma unroll
    for (int i = 0; i < 4; ++i) {
        const int n = i * 256 + t;
        const unsigned long long wd = msk[n >> 6];
        const int bit = n & 63;
        if ((wd >> bit) & 1ull) {
            int rank = wpre[n >> 6] + __popcll(wd & ((1ull << bit) - 1ull));
            if (rank < NSAMP) selr[rank] = n;
        }
    }
    __syncthreads();
    if (t < NSAMP) {
        const int n = selr[(t < cnt) ? t : 0];
        seln_g[(size_t)bid * NSAMP + t] = (unsigned short)n;
        lcsel_g[(size_t)bid * NSAMP + t] = lcall[n];
    }
    if (t == 0) cnt_g[bid] = cnt;
}

// ------- F-GEMM -------
__global__ __launch_bounds__(256) void fgemm_kernel(const float* __restrict__ feats,
                                                    const __bf16* __restrict__ W1f,
                                                    const float* __restrict__ s1,
                                                    const float* __restrict__ b1,
                                                    __bf16* __restrict__ Fsb) {
    __shared__ __align__(16) __bf16 Ft[16][LDFT];
    __shared__ __align__(16) __bf16 Fo[16][LDFO];
    const int t = threadIdx.x;
    const int b = blockIdx.x >> 7;
    const int half = (blockIdx.x >> 6) & 1;
    const int n0 = (blockIdx.x & 63) << 4;
    const int l = t & 63, w = t >> 6;
    const int lo = l & 15, kg = l >> 4;

    const float* fb = feats + (size_t)b * (CIN * NPTS) + n0;
    {
        const int n = t & 15;
        const int cq = (t >> 4) * 2;
        for (int i = 0; i < 16; ++i) {
            int c = i * 32 + cq;
            float v0 = fb[(size_t)c * NPTS + n];
            float v1v = fb[(size_t)(c + 1) * NPTS + n];
            bf16x2 pk = {(__bf16)v0, (__bf16)v1v};
            *(bf16x2*)(&Ft[n][c]) = pk;
        }
    }
    __syncthreads();

    f32x4 acc[2];
#pragma unroll
    for (int mt = 0; mt < 2; ++mt) acc[mt] = f32x4{0.f, 0.f, 0.f, 0.f};

#pragma unroll
    for (int ks = 0; ks < 16; ++ks) {
        const int kk = ks * 32 + kg * 8;
        const bf16x8 bfr = *(const bf16x8*)(&Ft[lo][kk]);
#pragma unroll
        for (int mt = 0; mt < 2; ++mt) {
            const int o = half * 128 + w * 32 + mt * 16 + lo;
            const bf16x8 af = *(const bf16x8*)(&W1f[(size_t)o * CIN + kk]);
            acc[mt] = __builtin_amdgcn_mfma_f32_16x16x32_bf16(af, bfr, acc[mt], 0, 0, 0);
        }
    }
    __syncthreads();
#pragma unroll
    for (int mt = 0; mt < 2; ++mt) {
        const int ol = w * 32 + mt * 16 + kg * 4;
        const f32x4 sv = *(const f32x4*)(&s1[half * 128 + ol]);
        const f32x4 bv = *(const f32x4*)(&b1[half * 128 + ol]);
        bf16x4 r;
#pragma unroll
        for (int j = 0; j < 4; ++j) r[j] = (__bf16)fmaf(acc[mt][j], sv[j], bv[j]);
        *(bf16x4*)(&Fo[lo][ol]) = r;
    }
    __syncthreads();
    {
        const int row = t >> 4, c = t & 15;
        const bf16x8 v = *(const bf16x8*)(&Fo[row][c * 8]);
        *(bf16x8*)(&Fsb[((size_t)(b * NPTS + n0 + row)) * 256 + half * 128 + c * 8]) = v;
    }
}

// -------- fused (R9, unchanged): weight-stationary, cnt-bounded GEMM2, P=8 --------
__global__ __launch_bounds__(512, 2) void fused_kernel(
    const __bf16* __restrict__ Fsb, const float* __restrict__ wxs,
    const unsigned short* __restrict__ seln_g, const int* __restrict__ cnt_g,
    const f32x4* __restrict__ lcsel_g,
    const __bf16* __restrict__ W2s, const float* __restrict__ s2g, const float* __restrict__ b2g,
    float* __restrict__ out) {
    __shared__ __align__(16) char A2raw[NSAMP * 512];
    __shared__ __align__(16) f32x4 lcL[8][NSAMP];
    __shared__ __align__(16) float outst[256][8];
    __shared__ unsigned short selL[8][NSAMP];
    __shared__ int cntL[8];

    const int raw = (int)blockIdx.x;
    const int pg = (raw & 7) * 32 + (raw >> 3);
    const int b = pg >> 7;
    const int p0 = (pg & 127) * 8;
    const int t = threadIdx.x;
    const int l = t & 63, w = t >> 6;
    const int lo = l & 15, kg = l >> 4;

    {
        const int pi = t >> 6, s = t & 63;
        const size_t base = ((size_t)(b * NPTS + p0 + pi)) * NSAMP + s;
        selL[pi][s] = seln_g[base];
        lcL[pi][s] = lcsel_g[base];
    }
    if (t < 8) cntL[t] = cnt_g[b * NPTS + p0 + t];

    bf16x8 wf[8][2];
#pragma unroll
    for (int ks = 0; ks < 8; ++ks)
#pragma unroll
        for (int nt = 0; nt < 2; ++nt)
            wf[ks][nt] = *(const bf16x8*)(&W2s[(size_t)((((w * 8 + ks) * 2 + nt) * 64) + l) * 8]);

    const int oc4 = (t & 63) * 4;
    const int g8 = t >> 6;
    f32x4 wv4[4];
#pragma unroll
    for (int j = 0; j < 4; ++j) wv4[j] = *(const f32x4*)(&wxs[(oc4 + j) * 4]);

    float sc[2], bb[2];
#pragma unroll
    for (int nt = 0; nt < 2; ++nt) {
        const int o = w * 32 + nt * 16 + lo;
        sc[nt] = s2g[o];
        bb[nt] = b2g[o];
    }
    __syncthreads();

    bf16x4 stg[8];
    {
        const int rpad = (min(cntL[0], NSAMP) + 15) & ~15;
#pragma unroll
        for (int si = 0; si < 8; ++si) {
            const int s = g8 * 8 + si;
            if (s < rpad)
                stg[si] = *(const bf16x4*)(&Fsb[((size_t)(b * NPTS + (int)selL[0][s])) * 256 + oc4]);
        }
#pragma unroll
        for (int si = 0; si < 8; ++si) {
            const int s = g8 * 8 + si;
            if (s < rpad) {
                const f32x4 cd = lcL[0][s];
#pragma unroll
                for (int j = 0; j < 4; ++j) {
                    const float x = fmaf(cd.x, wv4[j].x,
                                         fmaf(cd.y, wv4[j].y, fmaf(cd.z, wv4[j].z, (float)stg[si][j])));
                    stg[si][j] = (__bf16)fmaxf(x, 0.f);
                }
                *(bf16x4*)(A2raw + s * 512 + ((oc4 * 2) ^ ((s & 7) << 4))) = stg[si];
            }
        }
    }
    __syncthreads();

    for (int pi = 0; pi < 8; ++pi) {
        const int mtmax = (min(cntL[pi], NSAMP) + 15) >> 4;
        int rpadn = 0;
        if (pi < 7) {
            rpadn = (min(cntL[pi + 1], NSAMP) + 15) & ~15;
#pragma unroll
            for (int si = 0; si < 8; ++si) {
                const int s = g8 * 8 + si;
                if (s < rpadn)
                    stg[si] = *(const bf16x4*)(&Fsb[((size_t)(b * NPTS + (int)selL[pi + 1][s])) * 256 + oc4]);
            }
        }

        f32x4 acc[4][2];
#pragma unroll
        for (int mt = 0; mt < 4; ++mt)
#pragma unroll
            for (int nt = 0; nt < 2; ++nt)
                acc[mt][nt] = f32x4{0.f, 0.f, 0.f, 0.f};

#pragma unroll
        for (int mt = 0; mt < 4; ++mt) {
            if (mt < mtmax) {
                const int row = mt * 16 + lo;
#pragma unroll
                for (int ks = 0; ks < 8; ++ks) {
                    const bf16x8 a = *(const bf16x8*)(A2raw + row * 512 +
                                                      ((ks * 64 + kg * 16) ^ ((row & 7) << 4)));
                    acc[mt][0] = __builtin_amdgcn_mfma_f32_16x16x32_bf16(a, wf[ks][0],
                                                                         acc[mt][0], 0, 0, 0);
                    acc[mt][1] = __builtin_amdgcn_mfma_f32_16x16x32_bf16(a, wf[ks][1],
                                                                         acc[mt][1], 0, 0, 0);
                }
            }
        }

        if (pi < 7) {
#pragma unroll
            for (int si = 0; si < 8; ++si) {
                const int s = g8 * 8 + si;
                if (s < rpadn) {
                    const f32x4 cd = lcL[pi + 1][s];
#pragma unroll
                    for (int j = 0; j < 4; ++j) {
                        const float x = fmaf(cd.x, wv4[j].x,
                                             fmaf(cd.y, wv4[j].y, fmaf(cd.z, wv4[j].z, (float)stg[si][j])));
                        stg[si][j] = (__bf16)fmaxf(x, 0.f);
                    }
                }
            }
        }

#pragma unroll
        for (int nt = 0; nt < 2; ++nt) {
            float mx = 0.f;
#pragma unroll
            for (int mt = 0; mt < 4; ++mt) {
                if (mt < mtmax) {
#pragma unroll
                    for (int r = 0; r < 4; ++r)
                        mx = fmaxf(mx, fmaxf(fmaf(acc[mt][nt][r], sc[nt], bb[nt]), 0.f));
                }
            }
            mx = fmaxf(mx, __shfl_xor(mx, 16));
            mx = fmaxf(mx, __shfl_xor(mx, 32));
            if (kg == 0) outst[w * 32 + nt * 16 + lo][pi] = mx;
        }
        __syncthreads();

        if (pi < 7) {
#pragma unroll
            for (int si = 0; si < 8; ++si) {
                const int s = g8 * 8 + si;
                if (s < rpadn)
                    *(bf16x4*)(A2raw + s * 512 + ((oc4 * 2) ^ ((s & 7) << 4))) = stg[si];
            }
        }
        __syncthreads();
    }

    {
        const int o = t >> 1, hf = t & 1;
        const f32x4 v = *(const f32x4*)(&outst[o][hf * 4]);
        *(f32x4*)(&out[((size_t)b * 256 + o) * NPTS + p0 + hf * 4]) = v;
    }
}

// -------- fused_probe: ablation instrument. MODE 0=full, 1=gather-side, 2=gemm-side --------
template <int MODE, int REP>
__global__ __launch_bounds__(512, 2) void fused_probe(
    const __bf16* __restrict__ Fsb, const float* __restrict__ wxs,
    const unsigned short* __restrict__ seln_g, const int* __restrict__ cnt_g,
    const f32x4* __restrict__ lcsel_g,
    const __bf16* __restrict__ W2s, const float* __restrict__ s2g, const float* __restrict__ b2g,
    float* __restrict__ outp) {
    __shared__ __align__(16) char A2raw[NSAMP * 512];
    __shared__ __align__(16) f32x4 lcL[8][NSAMP];
    __shared__ __align__(16) float outst[256][8];
    __shared__ unsigned short selL[8][NSAMP];
    __shared__ int cntL[8];

    const int raw = (int)blockIdx.x;
    const int pg = (raw & 7) * 32 + (raw >> 3);
    const int b = pg >> 7;
    const int p0 = (pg & 127) * 8;
    const int t = threadIdx.x;
    const int l = t & 63, w = t >> 6;
    const int lo = l & 15, kg = l >> 4;

    {
        const int pi = t >> 6, s = t & 63;
        const size_t base = ((size_t)(b * NPTS + p0 + pi)) * NSAMP + s;
        selL[pi][s] = seln_g[base];
        lcL[pi][s] = lcsel_g[base];
    }
    if (t < 8) cntL[t] = cnt_g[b * NPTS + p0 + t];

    bf16x8 wf[8][2];
#pragma unroll
    for (int ks = 0; ks < 8; ++ks)
#pragma unroll
        for (int nt = 0; nt < 2; ++nt)
            wf[ks][nt] = *(const bf16x8*)(&W2s[(size_t)((((w * 8 + ks) * 2 + nt) * 64) + l) * 8]);

    const int oc4 = (t & 63) * 4;
    const int g8 = t >> 6;
    f32x4 wv4[4];
#pragma unroll
    for (int j = 0; j < 4; ++j) wv4[j] = *(const f32x4*)(&wxs[(oc4 + j) * 4]);

    float sc[2], bb[2];
#pragma unroll
    for (int nt = 0; nt < 2; ++nt) {
        const int o = w * 32 + nt * 16 + lo;
        sc[nt] = s2g[o];
        bb[nt] = b2g[o];
    }
    __syncthreads();

    bf16x4 stg[8];
    // prologue (all modes): gather + transform + A2 store for p0
    {
        const int rpad = (min(cntL[0], NSAMP) + 15) & ~15;
#pragma unroll
        for (int si = 0; si < 8; ++si) {
            const int s = g8 * 8 + si;
            if (s < rpad)
                stg[si] = *(const bf16x4*)(&Fsb[((size_t)(b * NPTS + (int)selL[0][s])) * 256 + oc4]);
        }
#pragma unroll
        for (int si = 0; si < 8; ++si) {
            const int s = g8 * 8 + si;
            if (s < rpad) {
                const f32x4 cd = lcL[0][s];
#pragma unroll
                for (int j = 0; j < 4; ++j) {
                    const float x = fmaf(cd.x, wv4[j].x,
                                         fmaf(cd.y, wv4[j].y, fmaf(cd.z, wv4[j].z, (float)stg[si][j])));
                    stg[si][j] = (__bf16)fmaxf(x, 0.f);
                }
                *(bf16x4*)(A2raw + s * 512 + ((oc4 * 2) ^ ((s & 7) << 4))) = stg[si];
            }
        }
    }
    __syncthreads();

    int opq = 0;  // opaque 0: blocks cross-rep hoisting of invariant LDS reads
    for (int rep = 0; rep < REP; ++rep) {
        asm volatile("" : "+v"(opq));
        float tkeep = 0.f;
        for (int pi = 0; pi < 8; ++pi) {
            const int mtmax = (min(cntL[pi], NSAMP) + 15) >> 4;
            int rpadn = 0;
            if (MODE != 2 && pi < 7) {
                rpadn = (min(cntL[pi + 1], NSAMP) + 15) & ~15;
#pragma unroll
                for (int si = 0; si < 8; ++si) {
                    const int s = g8 * 8 + si;
                    if (s < rpadn)
                        stg[si] = *(const bf16x4*)(&Fsb[((size_t)(b * NPTS + (int)selL[pi + 1][s])) * 256 + oc4]);
                }
            }

            f32x4 acc[4][2];
#pragma unroll
            for (int mt = 0; mt < 4; ++mt)
#pragma unroll
                for (int nt = 0; nt < 2; ++nt)
                    acc[mt][nt] = f32x4{0.f, 0.f, 0.f, 0.f};

            if (MODE != 1) {
#pragma unroll
                for (int mt = 0; mt < 4; ++mt) {
                    if (mt < mtmax) {
                        const int row = mt * 16 + lo;
#pragma unroll
                        for (int ks = 0; ks < 8; ++ks) {
                            const bf16x8 a = *(const bf16x8*)(A2raw + row * 512 +
                                                              (((ks * 64 + kg * 16) ^ ((row & 7) << 4)) + opq));
                            acc[mt][0] = __builtin_amdgcn_mfma_f32_16x16x32_bf16(a, wf[ks][0],
                                                                                 acc[mt][0], 0, 0, 0);
                            acc[mt][1] = __builtin_amdgcn_mfma_f32_16x16x32_bf16(a, wf[ks][1],
                                                                                 acc[mt][1], 0, 0, 0);
                        }
                    }
                }
            }

            if (MODE != 2 && pi < 7) {
#pragma unroll
                for (int si = 0; si < 8; ++si) {
                    const int s = g8 * 8 + si;
                    if (s < rpadn) {
                        const f32x4 cd = lcL[pi + 1][s];
#pragma unroll
                        for (int j = 0; j < 4; ++j) {
                            const float x = fmaf(cd.x, wv4[j].x,
                                                 fmaf(cd.y, wv4[j].y, fmaf(cd.z, wv4[j].z, (float)stg[si][j])));
                            stg[si][j] = (__bf16)fmaxf(x, 0.f);
                        }
                        tkeep += (float)stg[si][0];
                    }
                }
            }

#pragma unroll
            for (int nt = 0; nt < 2; ++nt) {
                float mx = (MODE == 1) ? tkeep : 0.f;
                if (MODE != 1) {
#pragma unroll
                    for (int mt = 0; mt < 4; ++mt) {
                        if (mt < mtmax) {
#pragma unroll
                            for (int r = 0; r < 4; ++r)
                                mx = fmaxf(mx, fmaxf(fmaf(acc[mt][nt][r], sc[nt], bb[nt]), 0.f));
                        }
                    }
                }
                mx = fmaxf(mx, __shfl_xor(mx, 16));
                mx = fmaxf(mx, __shfl_xor(mx, 32));
                if (kg == 0) outst[w * 32 + nt * 16 + lo][pi] = mx;
            }
            __syncthreads();  // BAR1

            if (MODE != 2 && pi < 7) {
#pragma unroll
                for (int si = 0; si < 8; ++si) {
                    const int s = g8 * 8 + si;
                    if (s < rpadn)
                        *(bf16x4*)(A2raw + s * 512 + ((oc4 * 2) ^ ((s & 7) << 4))) = stg[si];
                }
            }
            __syncthreads();  // BAR2
        }
    }

    {
        const int o = t >> 1, hf = t & 1;
        const f32x4 v = *(const f32x4*)(&outst[o][hf * 4]);
        *(f32x4*)(&outp[((size_t)b * 256 + o) * NPTS + p0 + hf * 4]) = v;
    }
}

extern "C" void kernel_launch(void* const* d_in, const int* in_sizes, int n_in,
                              void* d_out, int out_size, void* d_ws, size_t ws_size,
                              hipStream_t stream) {
    (void)in_sizes; (void)n_in; (void)out_size; (void)ws_size;
    const float* xyz   = (const float*)d_in[0];
    const float* feats = (const float*)d_in[1];
    const float* rot   = (const float*)d_in[2];
    const float* crop  = (const float*)d_in[3];
    const float* W1    = (const float*)d_in[4];
    const float* g1    = (const float*)d_in[5];
    const float* be1   = (const float*)d_in[6];
    const float* m1    = (const float*)d_in[7];
    const float* v1    = (const float*)d_in[8];
    const float* W2    = (const float*)d_in[9];
    const float* g2    = (const float*)d_in[10];
    const float* be2   = (const float*)d_in[11];
    const float* m2    = (const float*)d_in[12];
    const float* v2    = (const float*)d_in[13];

    char* ws = (char*)d_ws;
    __bf16* W1f = (__bf16*)(ws + 0);
    __bf16* W2s = (__bf16*)(ws + 262144);
    float*  wxs = (float*)(ws + 393216);
    float*  s1  = (float*)(ws + 397312);
    float*  b1  = (float*)(ws + 398336);
    float*  s2  = (float*)(ws + 399360);
    float*  b2  = (float*)(ws + 400384);
    __bf16* Fsb = (__bf16*)(ws + 401408);
    unsigned short* seln = (unsigned short*)(ws + 1449984);
    int*    cntg = (int*)(ws + 1712128);
    f32x4*  lcse = (f32x4*)(ws + 1720320);
    float*  po0  = (float*)(ws + 4194304);   // 8 MB scratch each
    float*  po1  = (float*)(ws + 12582912);
    float*  po2  = (float*)(ws + 20971520);

    setup_kernel<<<2304, 256, 0, stream>>>(xyz, rot, crop,
                                           W1, W2, g1, be1, m1, v1, g2, be2, m2, v2,
                                           W1f, W2s, wxs, s1, b1, s2, b2, seln, cntg, lcse);
    fgemm_kernel<<<256, 256, 0, stream>>>(feats, W1f, s1, b1, Fsb);
    fused_kernel<<<256, 512, 0, stream>>>(Fsb, wxs, seln, cntg, lcse, W2s, s2, b2,
                                          (float*)d_out);
    // ---- ablation probes (scratch output; timed but not correctness-relevant) ----
    fused_probe<0, 2><<<256, 512, 0, stream>>>(Fsb, wxs, seln, cntg, lcse, W2s, s2, b2, po0);
    fused_probe<1, 4><<<256, 512, 0, stream>>>(Fsb, wxs, seln, cntg, lcse, W2s, s2, b2, po1);
    fused_probe<2, 3><<<256, 512, 0, stream>>>(Fsb, wxs, seln, cntg, lcse, W2s, s2, b2, po2);
}

// Round 12
// 42.903 us; speedup vs baseline: 4.5627x; 4.5627x over previous
//
#include <hip/hip_runtime.h>
#include <hip/hip_bf16.h>
#include <math.h>

typedef __attribute__((ext_vector_type(8))) __bf16 bf16x8;
typedef __attribute__((ext_vector_type(4))) __bf16 bf16x4;
typedef __attribute__((ext_vector_type(2))) __bf16 bf16x2;
typedef __attribute__((ext_vector_type(4))) float f32x4;

#define NPTS 1024
#define CIN 512
#define NSAMP 64
#define LDFT 520
#define LDFO 136

__device__ __forceinline__ void local_coords(const float* q, float cx, float cy, float cz,
                                             const float R[9], float& l0, float& l1, float& l2) {
    float d0 = __fsub_rn(q[0], cx);
    float d1 = __fsub_rn(q[1], cy);
    float d2 = __fsub_rn(q[2], cz);
    l0 = __fadd_rn(__fadd_rn(__fmul_rn(d0, R[0]), __fmul_rn(d1, R[3])), __fmul_rn(d2, R[6]));
    l1 = __fadd_rn(__fadd_rn(__fmul_rn(d0, R[1]), __fmul_rn(d1, R[4])), __fmul_rn(d2, R[7]));
    l2 = __fadd_rn(__fadd_rn(__fmul_rn(d0, R[2]), __fmul_rn(d1, R[5])), __fmul_rn(d2, R[8]));
}

// -------- setup: blocks [0,256) = prep; blocks [256,2304) = select --------
__global__ __launch_bounds__(256) void setup_kernel(
    const float* __restrict__ xyz, const float* __restrict__ rot,
    const float* __restrict__ crop,
    const float* __restrict__ W1, const float* __restrict__ W2,
    const float* __restrict__ g1, const float* __restrict__ be1,
    const float* __restrict__ m1, const float* __restrict__ v1,
    const float* __restrict__ g2, const float* __restrict__ be2,
    const float* __restrict__ m2, const float* __restrict__ v2,
    __bf16* __restrict__ W1f, __bf16* __restrict__ W2s,
    float* __restrict__ wxs,
    float* __restrict__ s1, float* __restrict__ b1,
    float* __restrict__ s2, float* __restrict__ b2,
    unsigned short* __restrict__ seln_g, int* __restrict__ cnt_g,
    f32x4* __restrict__ lcsel_g) {
    __shared__ __align__(16) f32x4 lcall[NPTS];
    __shared__ unsigned long long msk[16];
    __shared__ int wpre[17];
    __shared__ int selr[NSAMP];

    const int t = threadIdx.x;
    if (blockIdx.x < 256) {
        const int o = blockIdx.x;
        if (t == 0) {
            float sc1 = g1[o] / sqrtf(v1[o] + 1e-5f);
            s1[o] = sc1;
            b1[o] = be1[o] - m1[o] * sc1;
            float sc2 = g2[o] / sqrtf(v2[o] + 1e-5f);
            s2[o] = sc2;
            b2[o] = be2[o] - m2[o] * sc2;
            wxs[o * 4 + 0] = sc1 * W1[o * 515 + 0];
            wxs[o * 4 + 1] = sc1 * W1[o * 515 + 1];
            wxs[o * 4 + 2] = sc1 * W1[o * 515 + 2];
            wxs[o * 4 + 3] = 0.f;
        }
        for (int k = t; k < CIN; k += blockDim.x)
            W1f[o * CIN + k] = (__bf16)W1[o * 515 + 3 + k];
        // W2s[f]: f = ((((w*8+ks)*2+nt)*64)+l)*8 + j ; o2=w*32+nt*16+(l&15), k=ks*32+(l>>4)*8+j
        {
            const int f = o * 256 + t;
            const int j = f & 7;
            const int l = (f >> 3) & 63;
            const int nt = (f >> 9) & 1;
            const int ks = (f >> 10) & 7;
            const int w = (f >> 13) & 7;
            const int o2 = w * 32 + nt * 16 + (l & 15);
            const int k = ks * 32 + ((l >> 4) << 3) + j;
            W2s[f] = (__bf16)W2[o2 * 256 + k];
        }
        return;
    }
    const int bid = blockIdx.x - 256;
    const int b = bid >> 10;
    const int l = t & 63, w = t >> 6;

    const float cx = xyz[bid * 3 + 0], cy = xyz[bid * 3 + 1], cz = xyz[bid * 3 + 2];
    float R[9];
#pragma unroll
    for (int j = 0; j < 9; ++j) R[j] = rot[bid * 9 + j];
    const float h0 = 0.5f * crop[bid * 3 + 0];
    const float h1 = 0.5f * crop[bid * 3 + 1];
    const float h2 = 0.5f * crop[bid * 3 + 2];

#pragma unroll
    for (int i = 0; i < 4; ++i) {
        const int n = i * 256 + t;
        float l0, l1, l2;
        local_coords(xyz + (size_t)(b * NPTS + n) * 3, cx, cy, cz, R, l0, l1, l2);
        lcall[n] = f32x4{l0, l1, l2, 0.f};
        bool ins = (__builtin_fabsf(l0) <= h0) && (__builtin_fabsf(l1) <= h1) &&
                   (__builtin_fabsf(l2) <= h2);
        unsigned long long bal = __ballot(ins);
        if (l == 0) msk[i * 4 + w] = bal;
    }
    __syncthreads();
    if (t < 64) {
        const int c = (t < 16) ? __popcll(msk[t]) : 0;
        int sum = c;
#pragma unroll
        for (int d = 1; d < 16; d <<= 1) {
            int v = __shfl_up(sum, d);
            if (t >= d) sum += v;
        }
        if (t < 16) wpre[t] = sum - c;
        if (t == 15) wpre[16] = sum;
    }
    __syncthreads();
    const int cnt = wpre[16];
#pragma unroll
    for (int i = 0; i < 4; ++i) {
        const int n = i * 256 + t;
        const unsigned long long wd = msk[n >> 6];
        const int bit = n & 63;
        if ((wd >> bit) & 1ull) {
            int rank = wpre[n >> 6] + __popcll(wd & ((1ull << bit) - 1ull));
            if (rank < NSAMP) selr[rank] = n;
        }
    }
    __syncthreads();
    if (t < NSAMP) {
        const int n = selr[(t < cnt) ? t : 0];
        seln_g[(size_t)bid * NSAMP + t] = (unsigned short)n;
        lcsel_g[(size_t)bid * NSAMP + t] = lcall[n];
    }
    if (t == 0) cnt_g[bid] = cnt;
}

// ------- F-GEMM -------
__global__ __launch_bounds__(256) void fgemm_kernel(const float* __restrict__ feats,
                                                    const __bf16* __restrict__ W1f,
                                                    const float* __restrict__ s1,
                                                    const float* __restrict__ b1,
                                                    __bf16* __restrict__ Fsb) {
    __shared__ __align__(16) __bf16 Ft[16][LDFT];
    __shared__ __align__(16) __bf16 Fo[16][LDFO];
    const int t = threadIdx.x;
    const int b = blockIdx.x >> 7;
    const int half = (blockIdx.x >> 6) & 1;
    const int n0 = (blockIdx.x & 63) << 4;
    const int l = t & 63, w = t >> 6;
    const int lo = l & 15, kg = l >> 4;

    const float* fb = feats + (size_t)b * (CIN * NPTS) + n0;
    {
        const int n = t & 15;
        const int cq = (t >> 4) * 2;
        for (int i = 0; i < 16; ++i) {
            int c = i * 32 + cq;
            float v0 = fb[(size_t)c * NPTS + n];
            float v1v = fb[(size_t)(c + 1) * NPTS + n];
            bf16x2 pk = {(__bf16)v0, (__bf16)v1v};
            *(bf16x2*)(&Ft[n][c]) = pk;
        }
    }
    __syncthreads();

    f32x4 acc[2];
#pragma unroll
    for (int mt = 0; mt < 2; ++mt) acc[mt] = f32x4{0.f, 0.f, 0.f, 0.f};

#pragma unroll
    for (int ks = 0; ks < 16; ++ks) {
        const int kk = ks * 32 + kg * 8;
        const bf16x8 bfr = *(const bf16x8*)(&Ft[lo][kk]);
#pragma unroll
        for (int mt = 0; mt < 2; ++mt) {
            const int o = half * 128 + w * 32 + mt * 16 + lo;
            const bf16x8 af = *(const bf16x8*)(&W1f[(size_t)o * CIN + kk]);
            acc[mt] = __builtin_amdgcn_mfma_f32_16x16x32_bf16(af, bfr, acc[mt], 0, 0, 0);
        }
    }
    __syncthreads();
#pragma unroll
    for (int mt = 0; mt < 2; ++mt) {
        const int ol = w * 32 + mt * 16 + kg * 4;
        const f32x4 sv = *(const f32x4*)(&s1[half * 128 + ol]);
        const f32x4 bv = *(const f32x4*)(&b1[half * 128 + ol]);
        bf16x4 r;
#pragma unroll
        for (int j = 0; j < 4; ++j) r[j] = (__bf16)fmaf(acc[mt][j], sv[j], bv[j]);
        *(bf16x4*)(&Fo[lo][ol]) = r;
    }
    __syncthreads();
    {
        const int row = t >> 4, c = t & 15;
        const bf16x8 v = *(const bf16x8*)(&Fo[row][c * 8]);
        *(bf16x8*)(&Fsb[((size_t)(b * NPTS + n0 + row)) * 256 + half * 128 + c * 8]) = v;
    }
}

// -------- fused: quad-batched A2 (4 p in LDS at once), 5 barriers, P=8 per block --------
// 256 blocks x 512 threads (8 waves); wave w owns o in [32w,32w+32) for GEMM.
// Gather mapping: oc4 = (t&63)*4, row-group g8 = t>>6 (8 rows per thread per p).
__global__ __launch_bounds__(512, 2) void fused_kernel(
    const __bf16* __restrict__ Fsb, const float* __restrict__ wxs,
    const unsigned short* __restrict__ seln_g, const int* __restrict__ cnt_g,
    const f32x4* __restrict__ lcsel_g,
    const __bf16* __restrict__ W2s, const float* __restrict__ s2g, const float* __restrict__ b2g,
    float* __restrict__ out) {
    __shared__ __align__(16) char A2raw[4 * NSAMP * 512];  // 128KB: quad of 4 p, reused q0/q1
    __shared__ __align__(16) f32x4 lcL[8][NSAMP];          // 8KB
    __shared__ __align__(16) float outst[256][8];          // 8KB
    __shared__ unsigned short selL[8][NSAMP];              // 1KB
    __shared__ int cntL[8];

    // XCD-chunked bijective swizzle (256 = 8 * 32)
    const int raw = (int)blockIdx.x;
    const int pg = (raw & 7) * 32 + (raw >> 3);
    const int b = pg >> 7;
    const int p0 = (pg & 127) * 8;
    const int t = threadIdx.x;
    const int l = t & 63, w = t >> 6;
    const int lo = l & 15, kg = l >> 4;

    // metadata fill: all 8 p (512 threads cover 8 x 64)
    {
        const int pi = t >> 6, s = t & 63;
        const size_t base = ((size_t)(b * NPTS + p0 + pi)) * NSAMP + s;
        selL[pi][s] = seln_g[base];
        lcL[pi][s] = lcsel_g[base];
    }
    if (t < 8) cntL[t] = cnt_g[b * NPTS + p0 + t];

    // W2 fragments -> registers (32 VGPR), resident whole kernel
    bf16x8 wf[8][2];
#pragma unroll
    for (int ks = 0; ks < 8; ++ks)
#pragma unroll
        for (int nt = 0; nt < 2; ++nt)
            wf[ks][nt] = *(const bf16x8*)(&W2s[(size_t)((((w * 8 + ks) * 2 + nt) * 64) + l) * 8]);

    const int oc4 = (t & 63) * 4;
    const int g8 = t >> 6;
    f32x4 wv4[4];
#pragma unroll
    for (int j = 0; j < 4; ++j) wv4[j] = *(const f32x4*)(&wxs[(oc4 + j) * 4]);

    float sc[2], bb[2];
#pragma unroll
    for (int nt = 0; nt < 2; ++nt) {
        const int o = w * 32 + nt * 16 + lo;
        sc[nt] = s2g[o];
        bb[nt] = b2g[o];
    }
    __syncthreads();  // BAR0: metadata ready

    bf16x4 stg[4][8];  // 64 VGPR staging: one quad's gathers
    int rp[4];

    // ---- quad 0: gather (all 32 loads in flight) + transform + store ----
#pragma unroll
    for (int pl = 0; pl < 4; ++pl) {
        rp[pl] = (min(cntL[pl], NSAMP) + 15) & ~15;
#pragma unroll
        for (int si = 0; si < 8; ++si) {
            const int s = g8 * 8 + si;
            if (s < rp[pl])
                stg[pl][si] = *(const bf16x4*)(&Fsb[((size_t)(b * NPTS + (int)selL[pl][s])) * 256 + oc4]);
        }
    }
#pragma unroll
    for (int pl = 0; pl < 4; ++pl) {
#pragma unroll
        for (int si = 0; si < 8; ++si) {
            const int s = g8 * 8 + si;
            if (s < rp[pl]) {
                const f32x4 cd = lcL[pl][s];
                bf16x4 r = stg[pl][si];
#pragma unroll
                for (int j = 0; j < 4; ++j) {
                    const float x = fmaf(cd.x, wv4[j].x,
                                         fmaf(cd.y, wv4[j].y, fmaf(cd.z, wv4[j].z, (float)r[j])));
                    r[j] = (__bf16)fmaxf(x, 0.f);
                }
                *(bf16x4*)(A2raw + (pl * NSAMP + s) * 512 + ((oc4 * 2) ^ ((s & 7) << 4))) = r;
            }
        }
    }
    // issue quad-1 gathers now (land during/before GEMM q0)
    int rp1[4];
#pragma unroll
    for (int pl = 0; pl < 4; ++pl) {
        rp1[pl] = (min(cntL[4 + pl], NSAMP) + 15) & ~15;
#pragma unroll
        for (int si = 0; si < 8; ++si) {
            const int s = g8 * 8 + si;
            if (s < rp1[pl])
                stg[pl][si] = *(const bf16x4*)(&Fsb[((size_t)(b * NPTS + (int)selL[4 + pl][s])) * 256 + oc4]);
        }
    }
    __syncthreads();  // BAR1: A2 quad0 ready

    // ---- GEMM quad 0 (4 p back-to-back, no barriers) ----
#pragma unroll
    for (int pl = 0; pl < 4; ++pl) {
        const int mtmax = (min(cntL[pl], NSAMP) + 15) >> 4;
        f32x4 acc[4][2];
#pragma unroll
        for (int mt = 0; mt < 4; ++mt)
#pragma unroll
            for (int nt = 0; nt < 2; ++nt)
                acc[mt][nt] = f32x4{0.f, 0.f, 0.f, 0.f};
#pragma unroll
        for (int mt = 0; mt < 4; ++mt) {
            if (mt < mtmax) {
                const int row = mt * 16 + lo;
#pragma unroll
                for (int ks = 0; ks < 8; ++ks) {
                    const bf16x8 a = *(const bf16x8*)(A2raw + (pl * NSAMP + row) * 512 +
                                                      ((ks * 64 + kg * 16) ^ ((row & 7) << 4)));
                    acc[mt][0] = __builtin_amdgcn_mfma_f32_16x16x32_bf16(a, wf[ks][0],
                                                                         acc[mt][0], 0, 0, 0);
                    acc[mt][1] = __builtin_amdgcn_mfma_f32_16x16x32_bf16(a, wf[ks][1],
                                                                         acc[mt][1], 0, 0, 0);
                }
            }
        }
#pragma unroll
        for (int nt = 0; nt < 2; ++nt) {
            float mx = 0.f;
#pragma unroll
            for (int mt = 0; mt < 4; ++mt) {
                if (mt < mtmax) {
#pragma unroll
                    for (int r = 0; r < 4; ++r)
                        mx = fmaxf(mx, fmaxf(fmaf(acc[mt][nt][r], sc[nt], bb[nt]), 0.f));
                }
            }
            mx = fmaxf(mx, __shfl_xor(mx, 16));
            mx = fmaxf(mx, __shfl_xor(mx, 32));
            if (kg == 0) outst[w * 32 + nt * 16 + lo][pl] = mx;
        }
    }
    __syncthreads();  // BAR2: A2 quad0 fully consumed

    // ---- quad 1: transform (loads already landed) + store ----
#pragma unroll
    for (int pl = 0; pl < 4; ++pl) {
#pragma unroll
        for (int si = 0; si < 8; ++si) {
            const int s = g8 * 8 + si;
            if (s < rp1[pl]) {
                const f32x4 cd = lcL[4 + pl][s];
                bf16x4 r = stg[pl][si];
#pragma unroll
                for (int j = 0; j < 4; ++j) {
                    const float x = fmaf(cd.x, wv4[j].x,
                                         fmaf(cd.y, wv4[j].y, fmaf(cd.z, wv4[j].z, (float)r[j])));
                    r[j] = (__bf16)fmaxf(x, 0.f);
                }
                *(bf16x4*)(A2raw + (pl * NSAMP + s) * 512 + ((oc4 * 2) ^ ((s & 7) << 4))) = r;
            }
        }
    }
    __syncthreads();  // BAR3: A2 quad1 ready

    // ---- GEMM quad 1 ----
#pragma unroll
    for (int pl = 0; pl < 4; ++pl) {
        const int mtmax = (min(cntL[4 + pl], NSAMP) + 15) >> 4;
        f32x4 acc[4][2];
#pragma unroll
        for (int mt = 0; mt < 4; ++mt)
#pragma unroll
            for (int nt = 0; nt < 2; ++nt)
                acc[mt][nt] = f32x4{0.f, 0.f, 0.f, 0.f};
#pragma unroll
        for (int mt = 0; mt < 4; ++mt) {
            if (mt < mtmax) {
                const int row = mt * 16 + lo;
#pragma unroll
                for (int ks = 0; ks < 8; ++ks) {
                    const bf16x8 a = *(const bf16x8*)(A2raw + (pl * NSAMP + row) * 512 +
                                                      ((ks * 64 + kg * 16) ^ ((row & 7) << 4)));
                    acc[mt][0] = __builtin_amdgcn_mfma_f32_16x16x32_bf16(a, wf[ks][0],
                                                                         acc[mt][0], 0, 0, 0);
                    acc[mt][1] = __builtin_amdgcn_mfma_f32_16x16x32_bf16(a, wf[ks][1],
                                                                         acc[mt][1], 0, 0, 0);
                }
            }
        }
#pragma unroll
        for (int nt = 0; nt < 2; ++nt) {
            float mx = 0.f;
#pragma unroll
            for (int mt = 0; mt < 4; ++mt) {
                if (mt < mtmax) {
#pragma unroll
                    for (int r = 0; r < 4; ++r)
                        mx = fmaxf(mx, fmaxf(fmaf(acc[mt][nt][r], sc[nt], bb[nt]), 0.f));
                }
            }
            mx = fmaxf(mx, __shfl_xor(mx, 16));
            mx = fmaxf(mx, __shfl_xor(mx, 32));
            if (kg == 0) outst[w * 32 + nt * 16 + lo][4 + pl] = mx;
        }
    }
    __syncthreads();  // BAR4

    // ---- coalesced output: out[b][o][p0..p0+7] ----
    {
        const int o = t >> 1, hf = t & 1;
        const f32x4 v = *(const f32x4*)(&outst[o][hf * 4]);
        *(f32x4*)(&out[((size_t)b * 256 + o) * NPTS + p0 + hf * 4]) = v;
    }
}

extern "C" void kernel_launch(void* const* d_in, const int* in_sizes, int n_in,
                              void* d_out, int out_size, void* d_ws, size_t ws_size,
                              hipStream_t stream) {
    (void)in_sizes; (void)n_in; (void)out_size; (void)ws_size;
    const float* xyz   = (const float*)d_in[0];
    const float* feats = (const float*)d_in[1];
    const float* rot   = (const float*)d_in[2];
    const float* crop  = (const float*)d_in[3];
    const float* W1    = (const float*)d_in[4];
    const float* g1    = (const float*)d_in[5];
    const float* be1   = (const float*)d_in[6];
    const float* m1    = (const float*)d_in[7];
    const float* v1    = (const float*)d_in[8];
    const float* W2    = (const float*)d_in[9];
    const float* g2    = (const float*)d_in[10];
    const float* be2   = (const float*)d_in[11];
    const float* m2    = (const float*)d_in[12];
    const float* v2    = (const float*)d_in[13];

    char* ws = (char*)d_ws;
    __bf16* W1f = (__bf16*)(ws + 0);
    __bf16* W2s = (__bf16*)(ws + 262144);
    float*  wxs = (float*)(ws + 393216);
    float*  s1  = (float*)(ws + 397312);
    float*  b1  = (float*)(ws + 398336);
    float*  s2  = (float*)(ws + 399360);
    float*  b2  = (float*)(ws + 400384);
    __bf16* Fsb = (__bf16*)(ws + 401408);
    unsigned short* seln = (unsigned short*)(ws + 1449984);
    int*    cntg = (int*)(ws + 1712128);
    f32x4*  lcse = (f32x4*)(ws + 1720320);

    setup_kernel<<<2304, 256, 0, stream>>>(xyz, rot, crop,
                                           W1, W2, g1, be1, m1, v1, g2, be2, m2, v2,
                                           W1f, W2s, wxs, s1, b1, s2, b2, seln, cntg, lcse);
    fgemm_kernel<<<256, 256, 0, stream>>>(feats, W1f, s1, b1, Fsb);
    fused_kernel<<<256, 512, 0, stream>>>(Fsb, wxs, seln, cntg, lcse, W2s, s2, b2,
                                          (float*)d_out);
}